// Round 5
// baseline (240.980 us; speedup 1.0000x reference)
//
#include <hip/hip_runtime.h>
#include <math.h>

#define B_DIM 8
#define T_DIM 512
#define H_DIM 768
#define NTOK 511       // T - 1
#define NLAY 9         // 13 - LAYER_START
#define LAYER_START 4
#define NBAND 35       // pairs with |i-j| <= 4 (all that's needed)
#define TCHUNK 128     // ceil(NTOK / 4 tokens-per-block)

// Per-block partial outputs and per-block var sums. Module globals so we never
// depend on d_ws. Every element is overwritten by wk_a before wk_r reads it,
// so 0xAA poisoning / stale state across calls is irrelevant. No atomics.
__device__ float g_part[B_DIM * TCHUNK * H_DIM];  // 3 MB
__device__ float g_varp[B_DIM * TCHUNK];

// banded Gram index: pair (lo, lo+d), d<=4 -> off(d)+lo, off(d)=9d-d(d-1)/2
#define BOFF(d) ((d)*9 - (d) * ((d)-1) / 2)

// 4 waves per block, one token per wave. grid = (TCHUNK, B_DIM).
// Segmented over H (3 x 256 floats) so peak live set ~100 VGPRs -> fits the
// 128-VGPR cap from (256,4) with NO spill (R3's (256,4) spilled because the
// unsegmented kernel held all 108 v-regs + 45 g-regs at once).
__global__ __launch_bounds__(256, 4) void wk_a(const float* __restrict__ ahs) {
  const int chunk = blockIdx.x;
  const int b = blockIdx.y;
  const int wave = threadIdx.x >> 6;
  const int lane = threadIdx.x & 63;
  const int t_raw = chunk * 4 + wave;
  const bool active = (t_raw < NTOK);
  const int t = active ? t_raw : (NTOK - 1);  // clamp: loads stay in bounds

  __shared__ float sG[4][36];          // per-wave banded Gram park
  __shared__ float lds_out[4][H_DIM];  // per-wave token contribution
  __shared__ float lds_var[4];

  const size_t LSTR = (size_t)B_DIM * T_DIM * H_DIM;  // layer stride (floats)
  const float* lay0 =
      ahs + (size_t)LAYER_START * LSTR + ((size_t)b * T_DIM + t) * H_DIM;

  // ---- banded 9x9 Gram, segmented over H: 3 passes of 9 x float4/lane ----
  float g[NBAND];
#pragma unroll
  for (int p = 0; p < NBAND; ++p) g[p] = 0.f;

#pragma unroll 1
  for (int s = 0; s < 3; ++s) {
    const float* p0 = lay0 + s * 256 + lane * 4;
    float4 vs[NLAY];
#pragma unroll
    for (int l = 0; l < NLAY; ++l)
      vs[l] = *reinterpret_cast<const float4*>(p0 + (size_t)l * LSTR);
#pragma unroll
    for (int d = 0; d <= 4; ++d) {
#pragma unroll
      for (int i = 0; i + d < NLAY; ++i) {
        const float4 x = vs[i], y = vs[i + d];
        g[BOFF(d) + i] += x.x * y.x + x.y * y.y + x.z * y.z + x.w * y.w;
      }
    }
  }

  // ---- butterfly all-reduce across the 64-lane wave (35 values) ----
#pragma unroll
  for (int off = 32; off > 0; off >>= 1) {
#pragma unroll
    for (int p = 0; p < NBAND; ++p) g[p] += __shfl_xor(g[p], off, 64);
  }

  // park Gram in LDS so later code can index it dynamically (no scratch spill)
  if (lane == 0) {
#pragma unroll
    for (int p = 0; p < NBAND; ++p) sG[wave][p] = g[p];
  }
  __syncthreads();

  // ---- per-lane k: window rows + Cholesky (R = upper chol of Gram == QR's R
  //      up to row signs, which provably cancel in align/novelty) ----
  const int k = lane < NLAY ? lane : NLAY - 1;
  const int nl = (k >= 2) ? 2 : 0;
  const int nrr = (NLAY - 1 - k) < 2 ? (NLAY - 1 - k) : 2;
  const int m = nl + nrr + 1;  // 3..5, self row last

  auto rowf = [&](int i) -> int {
    return (i < nl) ? (k - 2 + i) : ((i < nl + nrr) ? (k + 1 + i - nl) : k);
  };
  auto GK = [&](int i, int j) -> float {
    int a = rowf(i), c = rowf(j);
    int lo = a < c ? a : c;
    int d = (a < c ? c : a) - lo;  // 0..4 always (window span <= 4)
    return sG[wave][d * 9 - d * (d - 1) / 2 + lo];
  };

  float R[5][5];
#pragma unroll
  for (int j = 0; j < 5; ++j)
#pragma unroll
    for (int i = 0; i < 5; ++i) R[i][j] = 0.f;

#pragma unroll
  for (int j = 0; j < 5; ++j) {
    if (j < m) {
#pragma unroll
      for (int i = 0; i < 5; ++i) {
        if (i < j) {  // compile-time after unroll
          float s = GK(i, j);
#pragma unroll
          for (int p = 0; p < 4; ++p)
            if (p < i) s -= R[p][i] * R[p][j];
          R[i][j] = s / R[i][i];
        }
      }
      float sjj = GK(j, j);
#pragma unroll
      for (int p = 0; p < 4; ++p)
        if (p < j) sjj -= R[p][j] * R[p][j];
      R[j][j] = sqrtf(fmaxf(sjj, 0.f));
    }
  }

  // r = R[:, m-1]
  float r[5];
#pragma unroll
  for (int i = 0; i < 5; ++i)
    r[i] = (m == 3) ? R[i][2] : ((m == 4) ? R[i][3] : R[i][4]);

  // column-normalize Rsub = R[:m-1,:m-1], row means
  float rowmean[4] = {0.f, 0.f, 0.f, 0.f};
#pragma unroll
  for (int j = 0; j < 4; ++j) {
    if (j < m - 1) {
      float cn = 0.f;
#pragma unroll
      for (int i = 0; i < 4; ++i)
        if (i <= j) cn += R[i][j] * R[i][j];
      cn = fmaxf(sqrtf(cn), 1e-12f);
      float inv = 1.f / cn;
#pragma unroll
      for (int i = 0; i < 4; ++i)
        if (i < m - 1) rowmean[i] += R[i][j] * inv;
    }
  }

  const float inv_m1 = 1.f / (float)(m - 1);
  float dotv = 0.f, nrm2 = 0.f;
#pragma unroll
  for (int i = 0; i < 4; ++i) {
    if (i < m - 1) {
      dotv += (rowmean[i] * inv_m1) * r[i];
      nrm2 += r[i] * r[i];
    }
  }
  float align_raw = dotv / sqrtf(nrm2);
  float align_v = 1.f / (align_raw * (float)m * 2.f);
  float rlast = (m == 3) ? r[2] : ((m == 4) ? r[3] : r[4]);
  float nov_v = fabsf(rlast) / sqrtf(nrm2 + rlast * rlast);

  // ---- broadcast the 9 (align, nov) from lanes 0..8 to all lanes ----
  float al[NLAY], nv[NLAY];
  float asum = 0.f, nsum = 0.f;
#pragma unroll
  for (int l = 0; l < NLAY; ++l) {
    al[l] = __shfl(align_v, l, 64);
    nv[l] = __shfl(nov_v, l, 64);
    asum += al[l];
    nsum += nv[l];
  }
  float alpha[NLAY];
  float csum = 0.f;
#pragma unroll
  for (int l = 0; l < NLAY; ++l) {
    alpha[l] = al[l] / asum + nv[l] / nsum;
    csum += alpha[l];
  }
  const float inv_csum = 1.f / csum;

  // ---- adjacent-layer cosine sims -> sample variance (ddof=1) ----
  float sims[NLAY - 1];
  float smean = 0.f;
#pragma unroll
  for (int j = 0; j < NLAY - 1; ++j) {
    float num = sG[wave][BOFF(1) + j];
    float den = fmaxf(sqrtf(sG[wave][j]) * sqrtf(sG[wave][j + 1]), 1e-8f);
    sims[j] = num / den;
    smean += sims[j];
  }
  smean *= (1.f / 8.f);
  float var = 0.f;
#pragma unroll
  for (int j = 0; j < NLAY - 1; ++j) {
    float d = sims[j] - smean;
    var += d * d;
  }
  var *= (1.f / 7.f);
  if (!active) var = 0.f;  // inactive wave contributes exactly zero

  if (lane == 0) lds_var[wave] = var;

  // ---- weighted layer sum; re-read v from cache (input is L3-resident),
  //      segmented so the register footprint stays small ----
  float c[NLAY];
#pragma unroll
  for (int l = 0; l < NLAY; ++l) c[l] = var * alpha[l] * inv_csum;

#pragma unroll 1
  for (int s = 0; s < 3; ++s) {
    const float* p0 = lay0 + s * 256 + lane * 4;
    float4 o;
    o.x = 0.f; o.y = 0.f; o.z = 0.f; o.w = 0.f;
#pragma unroll
    for (int l = 0; l < NLAY; ++l) {
      const float4 vv = *reinterpret_cast<const float4*>(p0 + (size_t)l * LSTR);
      o.x += c[l] * vv.x;
      o.y += c[l] * vv.y;
      o.z += c[l] * vv.z;
      o.w += c[l] * vv.w;
    }
    *reinterpret_cast<float4*>(&lds_out[wave][s * 256 + lane * 4]) = o;
  }
  __syncthreads();

  // ---- cross-wave sum, one partial vector + one partial var per block ----
  float* dst = g_part + ((size_t)(b * TCHUNK + chunk)) * H_DIM;
#pragma unroll
  for (int s = 0; s < 3; ++s) {
    int h = s * 256 + threadIdx.x;
    float sum = lds_out[0][h] + lds_out[1][h] + lds_out[2][h] + lds_out[3][h];
    dst[h] = sum;
  }
  if (threadIdx.x == 0) {
    g_varp[b * TCHUNK + chunk] =
        lds_var[0] + lds_var[1] + lds_var[2] + lds_var[3];
  }
}

// grid = (3, B_DIM) x 256 threads: reduce 128 partials, divide by Ssum, write out
__global__ __launch_bounds__(256) void wk_r(float* __restrict__ out) {
  const int b = blockIdx.y;
  const int h = blockIdx.x * 256 + threadIdx.x;

  float acc = 0.f;
#pragma unroll 8
  for (int j = 0; j < TCHUNK; ++j)
    acc += g_part[((size_t)(b * TCHUNK + j)) * H_DIM + h];

  float ssum = 0.f;  // uniform address stream -> scalar loads
#pragma unroll 8
  for (int j = 0; j < TCHUNK; ++j) ssum += g_varp[b * TCHUNK + j];

  out[b * H_DIM + h] = acc / ssum;
}

extern "C" void kernel_launch(void* const* d_in, const int* in_sizes, int n_in,
                              void* d_out, int out_size, void* d_ws, size_t ws_size,
                              hipStream_t stream) {
  const float* ahs = (const float*)d_in[0];
  // d_in[1] = attention_mask: unused by the reference computation
  float* out = (float*)d_out;
  (void)d_ws; (void)ws_size;

  wk_a<<<dim3(TCHUNK, B_DIM), dim3(256), 0, stream>>>(ahs);
  wk_r<<<dim3(3, B_DIM), dim3(256), 0, stream>>>(out);
}

// Round 6
// 227.194 us; speedup vs baseline: 1.0607x; 1.0607x over previous
//
#include <hip/hip_runtime.h>
#include <math.h>

#define B_DIM 8
#define T_DIM 512
#define H_DIM 768
#define NTOK 511       // T - 1
#define NLAY 9         // 13 - LAYER_START
#define LAYER_START 4
#define NBAND 35       // pairs with |i-j| <= 4 (all that's needed)
#define TCHUNK 128     // ceil(NTOK / 4 tokens-per-block)

// Per-block partial outputs and per-block var sums. Module globals so we never
// depend on d_ws. Every element is overwritten by wk_a before wk_r reads it,
// so 0xAA poisoning / stale state across calls is irrelevant. No atomics.
__device__ float g_part[B_DIM * TCHUNK * H_DIM];  // 3 MB
__device__ float g_varp[B_DIM * TCHUNK];

// banded Gram index: pair (lo, lo+d), d<=4 -> off(d)+lo, off(d)=9d-d(d-1)/2
#define BOFF(d) ((d)*9 - (d) * ((d)-1) / 2)

// DPP move: returns the dpp-selected lane's value (0 for invalid lanes).
// VALU-pipe cross-lane — no DS pipe, no lgkmcnt round trip.
template <int CTRL>
__device__ __forceinline__ float dpp_mov(float x) {
  return __builtin_bit_cast(
      float, __builtin_amdgcn_update_dpp(0, __builtin_bit_cast(int, x), CTRL,
                                         0xF, 0xF, true));
}

// Full-wave (64-lane) sum via gfx9 DPP ladder; total lands in lane 63.
__device__ __forceinline__ float wave_sum_dpp(float x) {
  x += dpp_mov<0x111>(x);  // row_shr:1
  x += dpp_mov<0x112>(x);  // row_shr:2
  x += dpp_mov<0x114>(x);  // row_shr:4
  x += dpp_mov<0x118>(x);  // row_shr:8  -> lane 15 of each row = row sum
  x += dpp_mov<0x142>(x);  // row_bcast:15 -> lane31 = S0+S1, lane63 = S2+S3
  x += dpp_mov<0x143>(x);  // row_bcast:31 -> lane63 = S0+S1+S2+S3
  return x;
}

// 4 waves per block, one token per wave. grid = (TCHUNK, B_DIM).
// (256,2): 256-VGPR cap. Single-pass register-resident v (108 VGPRs) + banded
// g (35) + temps ~ 170 VGPRs -> no spill (R4-verified). DS butterfly replaced
// by DPP ladder: 0 DS ops in the reduction.
__global__ __launch_bounds__(256, 2) void wk_a(const float* __restrict__ ahs) {
  const int chunk = blockIdx.x;
  const int b = blockIdx.y;
  const int wave = threadIdx.x >> 6;
  const int lane = threadIdx.x & 63;
  const int t_raw = chunk * 4 + wave;
  const bool active = (t_raw < NTOK);
  const int t = active ? t_raw : (NTOK - 1);  // clamp: loads stay in bounds

  __shared__ float sG[4][36];          // per-wave banded Gram park
  __shared__ float lds_out[4][H_DIM];  // per-wave token contribution
  __shared__ float lds_var[4];

  const size_t LSTR = (size_t)B_DIM * T_DIM * H_DIM;  // layer stride (floats)
  const float* lay0 =
      ahs + (size_t)LAYER_START * LSTR + ((size_t)b * T_DIM + t) * H_DIM;

  // ---- load 9 layers x 12 floats (3 x float4 per lane), coalesced 16B/lane ----
  float4 v[NLAY][3];
#pragma unroll
  for (int l = 0; l < NLAY; ++l) {
    const float* base = lay0 + (size_t)l * LSTR;
#pragma unroll
    for (int s = 0; s < 3; ++s) {
      v[l][s] = *reinterpret_cast<const float4*>(base + s * 256 + lane * 4);
    }
  }

  // ---- banded 9x9 Gram: 35 pair dots over this lane's 12 columns ----
  float g[NBAND];
#pragma unroll
  for (int d = 0; d <= 4; ++d) {
#pragma unroll
    for (int i = 0; i + d < NLAY; ++i) {
      float s0 = 0.f;
#pragma unroll
      for (int s = 0; s < 3; ++s) {
        const float4 x = v[i][s], y = v[i + d][s];
        s0 += x.x * y.x + x.y * y.y + x.z * y.z + x.w * y.w;
      }
      g[BOFF(d) + i] = s0;
    }
  }

  // ---- DPP wave reduction (VALU pipe only); totals land in lane 63 ----
#pragma unroll
  for (int p = 0; p < NBAND; ++p) g[p] = wave_sum_dpp(g[p]);

  if (lane == 63) {
#pragma unroll
    for (int p = 0; p < NBAND; ++p) sG[wave][p] = g[p];
  }
  __syncthreads();

  // ---- per-lane k: window rows + Cholesky (R = upper chol of Gram == QR's R
  //      up to row signs, which provably cancel in align/novelty) ----
  const int k = lane < NLAY ? lane : NLAY - 1;
  const int nl = (k >= 2) ? 2 : 0;
  const int nrr = (NLAY - 1 - k) < 2 ? (NLAY - 1 - k) : 2;
  const int m = nl + nrr + 1;  // 3..5, self row last

  auto rowf = [&](int i) -> int {
    return (i < nl) ? (k - 2 + i) : ((i < nl + nrr) ? (k + 1 + i - nl) : k);
  };
  auto GK = [&](int i, int j) -> float {
    int a = rowf(i), c = rowf(j);
    int lo = a < c ? a : c;
    int d = (a < c ? c : a) - lo;  // 0..4 always (window span <= 4)
    return sG[wave][d * 9 - d * (d - 1) / 2 + lo];
  };

  float R[5][5];
#pragma unroll
  for (int j = 0; j < 5; ++j)
#pragma unroll
    for (int i = 0; i < 5; ++i) R[i][j] = 0.f;

#pragma unroll
  for (int j = 0; j < 5; ++j) {
    if (j < m) {
#pragma unroll
      for (int i = 0; i < 5; ++i) {
        if (i < j) {  // compile-time after unroll
          float s = GK(i, j);
#pragma unroll
          for (int p = 0; p < 4; ++p)
            if (p < i) s -= R[p][i] * R[p][j];
          R[i][j] = s / R[i][i];
        }
      }
      float sjj = GK(j, j);
#pragma unroll
      for (int p = 0; p < 4; ++p)
        if (p < j) sjj -= R[p][j] * R[p][j];
      R[j][j] = sqrtf(fmaxf(sjj, 0.f));
    }
  }

  // r = R[:, m-1]
  float r[5];
#pragma unroll
  for (int i = 0; i < 5; ++i)
    r[i] = (m == 3) ? R[i][2] : ((m == 4) ? R[i][3] : R[i][4]);

  // column-normalize Rsub = R[:m-1,:m-1], row means
  float rowmean[4] = {0.f, 0.f, 0.f, 0.f};
#pragma unroll
  for (int j = 0; j < 4; ++j) {
    if (j < m - 1) {
      float cn = 0.f;
#pragma unroll
      for (int i = 0; i < 4; ++i)
        if (i <= j) cn += R[i][j] * R[i][j];
      cn = fmaxf(sqrtf(cn), 1e-12f);
      float inv = 1.f / cn;
#pragma unroll
      for (int i = 0; i < 4; ++i)
        if (i < m - 1) rowmean[i] += R[i][j] * inv;
    }
  }

  const float inv_m1 = 1.f / (float)(m - 1);
  float dotv = 0.f, nrm2 = 0.f;
#pragma unroll
  for (int i = 0; i < 4; ++i) {
    if (i < m - 1) {
      dotv += (rowmean[i] * inv_m1) * r[i];
      nrm2 += r[i] * r[i];
    }
  }
  float align_raw = dotv / sqrtf(nrm2);
  float align_v = 1.f / (align_raw * (float)m * 2.f);
  float rlast = (m == 3) ? r[2] : ((m == 4) ? r[3] : r[4]);
  float nov_v = fabsf(rlast) / sqrtf(nrm2 + rlast * rlast);

  // ---- broadcast the 9 (align, nov) from lanes 0..8 to all lanes ----
  float al[NLAY], nv[NLAY];
  float asum = 0.f, nsum = 0.f;
#pragma unroll
  for (int l = 0; l < NLAY; ++l) {
    al[l] = __shfl(align_v, l, 64);
    nv[l] = __shfl(nov_v, l, 64);
    asum += al[l];
    nsum += nv[l];
  }
  float alpha[NLAY];
  float csum = 0.f;
#pragma unroll
  for (int l = 0; l < NLAY; ++l) {
    alpha[l] = al[l] / asum + nv[l] / nsum;
    csum += alpha[l];
  }
  const float inv_csum = 1.f / csum;

  // ---- adjacent-layer cosine sims -> sample variance (ddof=1) ----
  float sims[NLAY - 1];
  float smean = 0.f;
#pragma unroll
  for (int j = 0; j < NLAY - 1; ++j) {
    float num = sG[wave][BOFF(1) + j];
    float den = fmaxf(sqrtf(sG[wave][j]) * sqrtf(sG[wave][j + 1]), 1e-8f);
    sims[j] = num / den;
    smean += sims[j];
  }
  smean *= (1.f / 8.f);
  float var = 0.f;
#pragma unroll
  for (int j = 0; j < NLAY - 1; ++j) {
    float d = sims[j] - smean;
    var += d * d;
  }
  var *= (1.f / 7.f);
  if (!active) var = 0.f;  // inactive wave contributes exactly zero

  if (lane == 0) lds_var[wave] = var;

  // ---- weighted layer sum from register-resident v (no second read) ----
  float c[NLAY];
#pragma unroll
  for (int l = 0; l < NLAY; ++l) c[l] = var * alpha[l] * inv_csum;

#pragma unroll
  for (int s = 0; s < 3; ++s) {
    float4 o;
    o.x = 0.f; o.y = 0.f; o.z = 0.f; o.w = 0.f;
#pragma unroll
    for (int l = 0; l < NLAY; ++l) {
      o.x += c[l] * v[l][s].x;
      o.y += c[l] * v[l][s].y;
      o.z += c[l] * v[l][s].z;
      o.w += c[l] * v[l][s].w;
    }
    *reinterpret_cast<float4*>(&lds_out[wave][s * 256 + lane * 4]) = o;
  }
  __syncthreads();

  // ---- cross-wave sum, one partial vector + one partial var per block ----
  float* dst = g_part + ((size_t)(b * TCHUNK + chunk)) * H_DIM;
#pragma unroll
  for (int s = 0; s < 3; ++s) {
    int h = s * 256 + threadIdx.x;
    float sum = lds_out[0][h] + lds_out[1][h] + lds_out[2][h] + lds_out[3][h];
    dst[h] = sum;
  }
  if (threadIdx.x == 0) {
    g_varp[b * TCHUNK + chunk] =
        lds_var[0] + lds_var[1] + lds_var[2] + lds_var[3];
  }
}

// grid = (3, B_DIM) x 256 threads: reduce 128 partials, divide by Ssum, write out
__global__ __launch_bounds__(256) void wk_r(float* __restrict__ out) {
  const int b = blockIdx.y;
  const int h = blockIdx.x * 256 + threadIdx.x;

  float acc = 0.f;
#pragma unroll 8
  for (int j = 0; j < TCHUNK; ++j)
    acc += g_part[((size_t)(b * TCHUNK + j)) * H_DIM + h];

  float ssum = 0.f;  // uniform address stream -> scalar loads
#pragma unroll 8
  for (int j = 0; j < TCHUNK; ++j) ssum += g_varp[b * TCHUNK + j];

  out[b * H_DIM + h] = acc / ssum;
}

extern "C" void kernel_launch(void* const* d_in, const int* in_sizes, int n_in,
                              void* d_out, int out_size, void* d_ws, size_t ws_size,
                              hipStream_t stream) {
  const float* ahs = (const float*)d_in[0];
  // d_in[1] = attention_mask: unused by the reference computation
  float* out = (float*)d_out;
  (void)d_ws; (void)ws_size;

  wk_a<<<dim3(TCHUNK, B_DIM), dim3(256), 0, stream>>>(ahs);
  wk_r<<<dim3(3, B_DIM), dim3(256), 0, stream>>>(out);
}